// Round 2
// baseline (25738.913 us; speedup 1.0000x reference)
//
#include <hip/hip_runtime.h>
#include <cstdint>
#include <cstddef>

#define B_   32
#define T_   2048
#define OBS_ 64
#define FC_  256
#define ACT_ 100
#define H_   512
#define TC_  128
#define NCH_ 16

typedef __attribute__((ext_vector_type(4))) unsigned int u32x4;
typedef __attribute__((ext_vector_type(8))) short bf16x8;
typedef __attribute__((ext_vector_type(4))) float f32x4;

static __device__ __forceinline__ bf16x8 as_b(u32x4 v){ union{u32x4 u; bf16x8 b;} x; x.u=v; return x.b; }
static __device__ __forceinline__ unsigned short f2bf(float f){
  unsigned int u = __builtin_bit_cast(unsigned int, f);
  return (unsigned short)((u + 0x7fffu + ((u>>16)&1u)) >> 16);
}
static __device__ __forceinline__ float bf2f(unsigned short s){
  unsigned int u = ((unsigned int)s) << 16;
  return __builtin_bit_cast(float, u);
}
// exact 3-way bf16 split: v == hi + mid + lo to ~2^-26 relative
static __device__ __forceinline__ void split3(float v, unsigned short& h, unsigned short& m, unsigned short& l){
  h = f2bf(v);
  float r1 = v - bf2f(h);
  m = f2bf(r1);
  float r2 = r1 - bf2f(m);
  l = f2bf(r2);
}
static __device__ __forceinline__ u32x4 pack8(const unsigned short* v){
  u32x4 r;
  r.x = (unsigned)v[0] | ((unsigned)v[1]<<16);
  r.y = (unsigned)v[2] | ((unsigned)v[3]<<16);
  r.z = (unsigned)v[4] | ((unsigned)v[5]<<16);
  r.w = (unsigned)v[6] | ((unsigned)v[7]<<16);
  return r;
}

// ---- workspace layout (bytes) ----
// Xf:    [tl=128][bg=2][kk=12][plane=3][lane=64] u32x4  (x A-frags, K=384 pad, triple-split)
// Wf:    [hs=32][g=4][kk=28][plane=3][lane=64] u32x4    (combined [W;U] B-frags, K=896, triple)
// Wpf:   [ct=7][kk=16][plane=3][lane=64] u32x4          (W_proj B-frags, N pad 112, triple)
// HC:    [tl=128][bg=2][kk=16][plane=3][lane=64] u32x4  (h A-frags per step of chunk, triple)
// hglob: [slot=3][bg=2][kk=16][plane=3][lane=64] u32x4  (h exchange ring, triple)
// cstate:[b=32][512] double
// ctr:   [bg=2][T] int
static constexpr size_t XF_OFF    = 0;
static constexpr size_t XF_SZ     = (size_t)TC_*2*12*3*64*16;      // 9,437,184
static constexpr size_t WF_OFF    = XF_OFF + XF_SZ;
static constexpr size_t WF_SZ     = (size_t)32*4*28*3*64*16;       // 11,010,048
static constexpr size_t WPF_OFF   = WF_OFF + WF_SZ;
static constexpr size_t WPF_SZ    = (size_t)7*16*3*64*16;          // 344,064
static constexpr size_t HC_OFF    = WPF_OFF + WPF_SZ;
static constexpr size_t HC_SZ     = (size_t)TC_*2*16*3*64*16;      // 12,582,912
static constexpr size_t HGLOB_OFF = HC_OFF + HC_SZ;
static constexpr size_t HGLOB_SZ  = (size_t)3*2*16*3*64*16;        // 294,912
static constexpr size_t CST_OFF   = HGLOB_OFF + HGLOB_SZ;
static constexpr size_t CST_SZ    = (size_t)B_*H_*8;               // 131,072
static constexpr size_t CTR_OFF   = CST_OFF + CST_SZ;
static constexpr size_t CTR_SZ    = (size_t)2*T_*4;

// ---------------- P1: per-chunk x A-frags (obs MLP f64-accum + action embed, triple-split) ----------------
__global__ __launch_bounds__(256) void k_prep_x(
    const float* __restrict__ obs, const float* __restrict__ act,
    const float* __restrict__ Wobs, const float* __restrict__ bobs,
    const float* __restrict__ Wact, const float* __restrict__ bact,
    u32x4* __restrict__ Xf, int tbase)
{
  __shared__ float Wl[64][257];
  __shared__ float ol[32][64];
  __shared__ float xr[32][256];
  __shared__ float al[32];
  __shared__ float wal[100], bal[100], bol[256];
  int tl = blockIdx.x; int t = tbase + tl; int tid = threadIdx.x;
  for (int i = tid; i < 64*256; i += 256) Wl[i>>8][i&255] = Wobs[i];
  for (int i = tid; i < 32*64; i += 256)
    ol[i>>6][i&63] = obs[((size_t)(i>>6)*T_ + t)*OBS_ + (i&63)];
  if (tid < 32) al[tid] = act[(size_t)tid*T_ + t];
  if (tid < 100) { wal[tid] = Wact[tid]; bal[tid] = bact[tid]; }
  bol[tid] = bobs[tid];
  __syncthreads();
  { // thread = output col k, all 32 rows; f64 accumulation
    int k = tid;
    double accd[32];
#pragma unroll
    for (int r = 0; r < 32; ++r) accd[r] = 0.0;
    for (int kc = 0; kc < 64; kc += 8) {
      float w[8];
#pragma unroll
      for (int q = 0; q < 8; ++q) w[q] = Wl[kc+q][k];
#pragma unroll
      for (int r = 0; r < 32; ++r) {
#pragma unroll
        for (int q = 0; q < 8; ++q) accd[r] += (double)w[q]*(double)ol[r][kc+q];
      }
    }
#pragma unroll
    for (int r = 0; r < 32; ++r) xr[r][k] = fmaxf((float)(accd[r] + (double)bol[k]), 0.f);
  }
  __syncthreads();
  int g = tid >> 6, l = tid & 63;
  int r = l & 15, sub = l >> 4;
  for (int p = g; p < 24; p += 4) {
    int bg = p / 12, kk = p % 12;
    int b = bg*16 + r;
    unsigned short vh[8], vm[8], vl[8];
#pragma unroll
    for (int j = 0; j < 8; ++j) {
      int k = kk*32 + sub*8 + j;
      float x;
      if (k < 256)      x = xr[b][k];
      else if (k < 356) {
        double tmp = (double)al[b]*(double)wal[k-256] + (double)bal[k-256];
        x = fmaxf((float)tmp, 0.f);
      } else            x = 0.f;
      split3(x, vh[j], vm[j], vl[j]);
    }
    size_t base = ((((size_t)tl*2 + bg)*12 + kk)*3)*64 + l;
    Xf[base]       = pack8(vh);
    Xf[base + 64]  = pack8(vm);
    Xf[base + 128] = pack8(vl);
  }
}

// ---------------- P2: combined [W_lstm; U_lstm] B-frags, triple-split ----------------
__global__ __launch_bounds__(256) void k_prep_w(
    const float* __restrict__ Wl, const float* __restrict__ Ul,
    unsigned short* __restrict__ Wf)
{
  size_t gid = (size_t)blockIdx.x*256 + threadIdx.x;
  if (gid >= (size_t)896*2048) return;
  int k = (int)(gid >> 11), oc = (int)(gid & 2047);
  float v = 0.f;
  if (k < 356) v = Wl[(size_t)k*2048 + oc];
  else if (k >= 384) v = Ul[(size_t)(k-384)*2048 + oc];
  unsigned short vh, vm, vlo;
  split3(v, vh, vm, vlo);
  int g = oc >> 9, hs = (oc & 511) >> 4, u = oc & 15;
  int kk = k >> 5, sub = (k >> 3) & 3, j = k & 7;
  size_t e = ((((size_t)(hs*4 + g)*28 + kk)*3 + 0)*64 + (sub*16 + u))*8 + j;
  Wf[e]        = vh;
  Wf[e + 512]  = vm;   // plane stride = 64 lanes * 8 ushorts
  Wf[e + 1024] = vlo;
}

// ---------------- P3: W_proj B-frags, triple-split, cols padded to 112 ----------------
__global__ __launch_bounds__(256) void k_prep_wp(
    const float* __restrict__ Wp, unsigned short* __restrict__ Wpf)
{
  int gid = blockIdx.x*256 + threadIdx.x;
  if (gid >= 512*112) return;
  int k = gid / 112, c = gid % 112;
  float v = (c < 100) ? Wp[(size_t)k*100 + c] : 0.f;
  unsigned short vh, vm, vlo;
  split3(v, vh, vm, vlo);
  int ct = c >> 4, cl = c & 15;
  int kk = k >> 5, sub = (k >> 3) & 3, j = k & 7;
  size_t e = (((size_t)(ct*16 + kk)*3 + 0)*64 + (sub*16 + cl))*8 + j;
  Wpf[e]        = vh;
  Wpf[e + 512]  = vm;
  Wpf[e + 1024] = vlo;
}

// ---------------- R: persistent cooperative LSTM (one chunk of 128 steps) ----------------
// grid 64 = 2 batch-groups x 32 hidden-slices; 256 thr = 4 waves (wave = gate, full K)
__global__ __launch_bounds__(256, 1) void k_rnn(
    const u32x4* __restrict__ Xf, const u32x4* __restrict__ Wf,
    const float* __restrict__ blstm,
    unsigned int* __restrict__ HC32,
    unsigned int* __restrict__ hglob32, const u32x4* __restrict__ hglob,
    int* __restrict__ ctr, double* __restrict__ cstate, int tbase)
{
  __shared__ double zbuf[4][16][16];
  __shared__ unsigned short hb0[16][16], hb1[16][16], hb2[16][16];
  int wg = blockIdx.x;
  int bg = wg >> 5, hs = wg & 31;
  int tid = threadIdx.x;
  int w = tid >> 6, lane = tid & 63;
  // triple-split weights resident in registers for the whole chunk (336 VGPRs)
  u32x4 Breg[28][3];
  {
    const u32x4* bp = Wf + ((size_t)(hs*4 + w)*28*3)*64 + lane;
#pragma unroll
    for (int f = 0; f < 28; ++f)
#pragma unroll
      for (int p = 0; p < 3; ++p)
        Breg[f][p] = bp[((size_t)f*3 + p)*64];
  }
  int gr = tid >> 4, gu = tid & 15;
  double bi  = (double)blstm[0*512 + hs*16 + gu];
  double bff = (double)blstm[1*512 + hs*16 + gu];
  double bgg = (double)blstm[2*512 + hs*16 + gu];
  double bo  = (double)blstm[3*512 + hs*16 + gu];
  double c = cstate[(size_t)(bg*16 + gr)*512 + hs*16 + gu];

#pragma unroll 1
  for (int tl = 0; tl < TC_; ++tl) {
    int gt = tbase + tl;
    int sr = (gt + 2) % 3;   // slot holding h from step gt-1
    const u32x4* xp = Xf + (((size_t)tl*2 + bg)*12*3)*64 + lane;
    const u32x4* hp = hglob + (((size_t)sr*2 + bg)*16*3)*64 + lane;
    f32x4 a0 = {0,0,0,0}, a1 = {0,0,0,0}, a2 = {0,0,0,0};
    f32x4 a3 = {0,0,0,0}, a4 = {0,0,0,0}, a5 = {0,0,0,0};
#pragma unroll
    for (int f = 0; f < 28; ++f) {
      u32x4 xa0, xa1, xa2;
      if (f < 12) {
        xa0 = xp[(f*3+0)*64]; xa1 = xp[(f*3+1)*64]; xa2 = xp[(f*3+2)*64];
      } else {
        int kk = f - 12;
        xa0 = hp[(kk*3+0)*64]; xa1 = hp[(kk*3+1)*64]; xa2 = hp[(kk*3+2)*64];
      }
      // 6-term product expansion: hh + (hm+mh) + (hl+lh+mm); independent acc chains
      a0 = __builtin_amdgcn_mfma_f32_16x16x32_bf16(as_b(xa0), as_b(Breg[f][0]), a0, 0,0,0);
      a1 = __builtin_amdgcn_mfma_f32_16x16x32_bf16(as_b(xa0), as_b(Breg[f][1]), a1, 0,0,0);
      a2 = __builtin_amdgcn_mfma_f32_16x16x32_bf16(as_b(xa1), as_b(Breg[f][0]), a2, 0,0,0);
      a3 = __builtin_amdgcn_mfma_f32_16x16x32_bf16(as_b(xa0), as_b(Breg[f][2]), a3, 0,0,0);
      a4 = __builtin_amdgcn_mfma_f32_16x16x32_bf16(as_b(xa2), as_b(Breg[f][0]), a4, 0,0,0);
      a5 = __builtin_amdgcn_mfma_f32_16x16x32_bf16(as_b(xa1), as_b(Breg[f][1]), a5, 0,0,0);
    }
#pragma unroll
    for (int q = 0; q < 4; ++q) {
      double z = (((double)a3[q] + (double)a4[q]) + (double)a5[q])
               + ((double)a1[q] + (double)a2[q]) + (double)a0[q];
      zbuf[w][(lane>>4)*4 + q][lane & 15] = z;
    }
    __syncthreads();
    { // gates in f64: one thread per (batch-local, hid-local)
      double zi = zbuf[0][gr][gu] + bi;
      double zf = zbuf[1][gr][gu] + bff;
      double zg = zbuf[2][gr][gu] + bgg;
      double zo = zbuf[3][gr][gu] + bo;
      double i_ = 1.0/(1.0 + exp(-zi));
      double f_ = 1.0/(1.0 + exp(-zf));
      double g_ = tanh(zg);
      double o_ = 1.0/(1.0 + exp(-zo));
      c = f_*c + i_*g_;
      double h = o_*tanh(c);
      unsigned short hh, hm, hl;
      split3((float)h, hh, hm, hl);
      hb0[gr][gu] = hh; hb1[gr][gu] = hm; hb2[gr][gu] = hl;
    }
    __syncthreads();
    if (tid < 128) { // pack h pairs into exchange ring + chunk history (writer-side frag layout)
      int r2 = tid >> 3, p8 = tid & 7;
      int hg0 = hs*16 + 2*p8;
      int kk = hg0 >> 5, sub = (hg0 >> 3) & 3, j = hg0 & 7;
      int lw = sub*16 + r2;
      int sw = gt % 3;
      unsigned int v0 = (unsigned)hb0[r2][2*p8] | ((unsigned)hb0[r2][2*p8+1] << 16);
      unsigned int v1 = (unsigned)hb1[r2][2*p8] | ((unsigned)hb1[r2][2*p8+1] << 16);
      unsigned int v2 = (unsigned)hb2[r2][2*p8] | ((unsigned)hb2[r2][2*p8+1] << 16);
      size_t dg = ((((size_t)sw*2 + bg)*16 + kk)*3 + 0)*256 + lw*4 + (j>>1);
      hglob32[dg]       = v0;
      hglob32[dg + 256] = v1;
      hglob32[dg + 512] = v2;
      size_t dc = ((((size_t)tl*2 + bg)*16 + kk)*3 + 0)*256 + lw*4 + (j>>1);
      HC32[dc]       = v0;
      HC32[dc + 256] = v1;
      HC32[dc + 512] = v2;
    }
    __syncthreads();   // drains each thread's stores (vmcnt) before arrive
    if (tid == 0) {
      __threadfence();                       // wb -> h visible at device scope
      atomicAdd(&ctr[bg*T_ + gt], 1);
      while (__hip_atomic_load(&ctr[bg*T_ + gt], __ATOMIC_RELAXED, __HIP_MEMORY_SCOPE_AGENT) < 32)
        __builtin_amdgcn_s_sleep(1);
      __threadfence();                       // inv L1 -> fresh h next step
    }
    __syncthreads();
  }
  cstate[(size_t)(bg*16 + gr)*512 + hs*16 + gu] = c;
}

// ---------------- L: logits + softmax(pi) for one chunk ----------------
// grid = TC_*2 blocks (tl, bg); 256 thr = 4 waves; wave w covers col-tiles {w, w+4}
__global__ __launch_bounds__(256) void k_logits(
    const u32x4* __restrict__ HC, const u32x4* __restrict__ Wpf,
    const float* __restrict__ bproj, float* __restrict__ out, int tbase)
{
  __shared__ float zl[16][120];
  int bid = blockIdx.x;
  int tl = bid >> 1, bg = bid & 1;
  int tid = threadIdx.x;
  int w = tid >> 6, lane = tid & 63;
  u32x4 a[16][3];
  {
    const u32x4* hp = HC + (((size_t)tl*2 + bg)*16*3)*64 + lane;
#pragma unroll
    for (int kk = 0; kk < 16; ++kk)
#pragma unroll
      for (int p = 0; p < 3; ++p)
        a[kk][p] = hp[(kk*3 + p)*64];
  }
  for (int ct = w; ct < 7; ct += 4) {
    f32x4 c0 = {0,0,0,0}, c1 = {0,0,0,0}, c2 = {0,0,0,0};
    f32x4 c3 = {0,0,0,0}, c4 = {0,0,0,0}, c5 = {0,0,0,0};
    const u32x4* bp2 = Wpf + ((size_t)ct*16*3)*64 + lane;
#pragma unroll
    for (int kk = 0; kk < 16; ++kk) {
      u32x4 b0 = bp2[(kk*3+0)*64], b1 = bp2[(kk*3+1)*64], b2 = bp2[(kk*3+2)*64];
      c0 = __builtin_amdgcn_mfma_f32_16x16x32_bf16(as_b(a[kk][0]), as_b(b0), c0, 0,0,0);
      c1 = __builtin_amdgcn_mfma_f32_16x16x32_bf16(as_b(a[kk][0]), as_b(b1), c1, 0,0,0);
      c2 = __builtin_amdgcn_mfma_f32_16x16x32_bf16(as_b(a[kk][1]), as_b(b0), c2, 0,0,0);
      c3 = __builtin_amdgcn_mfma_f32_16x16x32_bf16(as_b(a[kk][0]), as_b(b2), c3, 0,0,0);
      c4 = __builtin_amdgcn_mfma_f32_16x16x32_bf16(as_b(a[kk][2]), as_b(b0), c4, 0,0,0);
      c5 = __builtin_amdgcn_mfma_f32_16x16x32_bf16(as_b(a[kk][1]), as_b(b1), c5, 0,0,0);
    }
    int col = ct*16 + (lane & 15);
    float bv = (col < 100) ? bproj[col] : 0.f;
#pragma unroll
    for (int q = 0; q < 4; ++q) {
      double z = (((double)c3[q] + (double)c4[q]) + (double)c5[q])
               + ((double)c1[q] + (double)c2[q]) + (double)c0[q] + (double)bv;
      zl[(lane>>4)*4 + q][col] = (float)z;
    }
  }
  __syncthreads();
  int row = tid >> 4, l16 = tid & 15;
  float vv[7];
  float m = -1e30f;
#pragma unroll
  for (int k2 = 0; k2 < 7; ++k2) {
    int col = l16 + 16*k2;
    vv[k2] = (col < 100) ? zl[row][col] : -1e30f;
    m = fmaxf(m, vv[k2]);
  }
#pragma unroll
  for (int d = 1; d < 16; d <<= 1) m = fmaxf(m, __shfl_xor(m, d, 64));
  float s = 0.f; float ek[7];
#pragma unroll
  for (int k2 = 0; k2 < 7; ++k2) {
    int col = l16 + 16*k2;
    ek[k2] = (col < 100) ? expf(vv[k2] - m) : 0.f;
    s += ek[k2];
  }
#pragma unroll
  for (int d = 1; d < 16; d <<= 1) s += __shfl_xor(s, d, 64);
  int t = tbase + tl; int b = bg*16 + row;
  float* piout = out;
  float* lgout = out + 6553600ull;
#pragma unroll
  for (int k2 = 0; k2 < 7; ++k2) {
    int col = l16 + 16*k2;
    if (col < 100) {
      size_t idx = ((size_t)b*T_ + t)*100 + col;
      lgout[idx] = vv[k2];
      piout[idx] = ek[k2] / s;
    }
  }
}

// ---------------- A: argmax over batch axis (first-max semantics) ----------------
__global__ __launch_bounds__(128) void k_argmax(
    const float* __restrict__ lg, float* __restrict__ outA)
{
  int t = blockIdx.x, j = threadIdx.x;
  if (j >= 100) return;
  float best = lg[(size_t)t*100 + j];
  int bi = 0;
  for (int b = 1; b < 32; ++b) {
    float v = lg[((size_t)b*T_ + t)*100 + j];
    if (v > best) { best = v; bi = b; }
  }
  outA[(size_t)t*100 + j] = (float)bi;
}

extern "C" void kernel_launch(void* const* d_in, const int* in_sizes, int n_in,
                              void* d_out, int out_size, void* d_ws, size_t ws_size,
                              hipStream_t stream) {
  const float* obs  = (const float*)d_in[0];
  const float* act  = (const float*)d_in[1];
  const float* Wobs = (const float*)d_in[2];
  const float* bobs = (const float*)d_in[3];
  const float* Wact = (const float*)d_in[4];
  const float* bact = (const float*)d_in[5];
  const float* Wl   = (const float*)d_in[6];
  const float* Ul   = (const float*)d_in[7];
  const float* bl   = (const float*)d_in[8];
  const float* Wp   = (const float*)d_in[9];
  const float* bp   = (const float*)d_in[10];
  char* ws = (char*)d_ws;
  u32x4* Xf             = (u32x4*)(ws + XF_OFF);
  unsigned short* WfS   = (unsigned short*)(ws + WF_OFF);
  unsigned short* WpfS  = (unsigned short*)(ws + WPF_OFF);
  unsigned int* HC32    = (unsigned int*)(ws + HC_OFF);
  unsigned int* hglob32 = (unsigned int*)(ws + HGLOB_OFF);
  double* cstate        = (double*)(ws + CST_OFF);
  int* ctr              = (int*)(ws + CTR_OFF);
  float* out = (float*)d_out;

  // zero exchange ring + c-state + step counters (covers replay determinism)
  hipMemsetAsync(ws + HGLOB_OFF, 0, HGLOB_SZ + CST_SZ + CTR_SZ, stream);
  k_prep_w<<<7168, 256, 0, stream>>>(Wl, Ul, WfS);
  k_prep_wp<<<(512*112 + 255)/256, 256, 0, stream>>>(Wp, WpfS);
  for (int ch = 0; ch < NCH_; ++ch) {
    int tb = ch * TC_;
    k_prep_x<<<TC_, 256, 0, stream>>>(obs, act, Wobs, bobs, Wact, bact, Xf, tb);
    k_rnn<<<64, 256, 0, stream>>>(Xf, (const u32x4*)WfS, bl, HC32,
                                  hglob32, (const u32x4*)hglob32, ctr, cstate, tb);
    k_logits<<<TC_*2, 256, 0, stream>>>((const u32x4*)HC32, (const u32x4*)WpfS, bp, out, tb);
  }
  k_argmax<<<T_, 128, 0, stream>>>(out + 6553600ull, out + 13107200ull);
}

// Round 3
// 10611.778 us; speedup vs baseline: 2.4255x; 2.4255x over previous
//
#include <hip/hip_runtime.h>
#include <cstdint>
#include <cstddef>

#define B_   32
#define T_   2048
#define OBS_ 64
#define FC_  256
#define ACT_ 100
#define H_   512
#define TC_  128
#define NCH_ 16

typedef __attribute__((ext_vector_type(4))) unsigned int u32x4;
typedef __attribute__((ext_vector_type(8))) short bf16x8;
typedef __attribute__((ext_vector_type(4))) float f32x4;

static __device__ __forceinline__ bf16x8 as_b(u32x4 v){ union{u32x4 u; bf16x8 b;} x; x.u=v; return x.b; }
static __device__ __forceinline__ unsigned short f2bf(float f){
  unsigned int u = __builtin_bit_cast(unsigned int, f);
  return (unsigned short)((u + 0x7fffu + ((u>>16)&1u)) >> 16);
}
static __device__ __forceinline__ float bf2f(unsigned short s){
  unsigned int u = ((unsigned int)s) << 16;
  return __builtin_bit_cast(float, u);
}
static __device__ __forceinline__ void split3(float v, unsigned short& h, unsigned short& m, unsigned short& l){
  h = f2bf(v);
  float r1 = v - bf2f(h);
  m = f2bf(r1);
  float r2 = r1 - bf2f(m);
  l = f2bf(r2);
}
static __device__ __forceinline__ u32x4 pack8(const unsigned short* v){
  u32x4 r;
  r.x = (unsigned)v[0] | ((unsigned)v[1]<<16);
  r.y = (unsigned)v[2] | ((unsigned)v[3]<<16);
  r.z = (unsigned)v[4] | ((unsigned)v[5]<<16);
  r.w = (unsigned)v[6] | ((unsigned)v[7]<<16);
  return r;
}
// agent-coherent 16B load (bypasses L1/L2 -> LLC). Reads data published by
// other XCDs' sc1 stores without any cache-invalidate fence.
static __device__ __forceinline__ u32x4 load_cohx4(const unsigned int* p){
  u32x4 r;
  asm volatile("global_load_dwordx4 %0, %1, off sc0 sc1"
               : "=v"(r) : "v"(p) : "memory");
  return r;
}

// ---- workspace layout (bytes) ----
static constexpr size_t XF_OFF    = 0;
static constexpr size_t XF_SZ     = (size_t)TC_*2*12*3*64*16;      // x A-frags (triple)
static constexpr size_t WF_OFF    = XF_OFF + XF_SZ;
static constexpr size_t WF_SZ     = (size_t)32*4*28*3*64*16;       // [W;U] B-frags (triple)
static constexpr size_t WPF_OFF   = WF_OFF + WF_SZ;
static constexpr size_t WPF_SZ    = (size_t)7*16*3*64*16;          // W_proj B-frags
static constexpr size_t ZX_OFF    = WPF_OFF + WPF_SZ;
static constexpr size_t ZX_SZ     = (size_t)TC_*2*16*2048*4;       // x-side gate preact, f32
static constexpr size_t HC01_OFF  = ZX_OFF + ZX_SZ;
static constexpr size_t HC01_SZ   = (size_t)TC_*2*16*512*4;        // h planes 0|1 packed u32
static constexpr size_t HC2_OFF   = HC01_OFF + HC01_SZ;
static constexpr size_t HC2_SZ    = (size_t)TC_*2*16*512*2;        // h plane 2 u16
static constexpr size_t HG_OFF    = HC2_OFF + HC2_SZ;
static constexpr size_t HG_SZ     = (size_t)3*2*16*2*256*4;        // h exchange ring (frag layout)
static constexpr size_t CST_OFF   = HG_OFF + HG_SZ;
static constexpr size_t CST_SZ    = (size_t)B_*H_*8;               // c state f64
static constexpr size_t CTR_OFF   = CST_OFF + CST_SZ;
static constexpr size_t CTR_SZ    = (size_t)2*T_*4;

// ---------------- P1: per-chunk x A-frags (obs MLP f64-accum + action embed, triple-split) ----------------
__global__ __launch_bounds__(256) void k_prep_x(
    const float* __restrict__ obs, const float* __restrict__ act,
    const float* __restrict__ Wobs, const float* __restrict__ bobs,
    const float* __restrict__ Wact, const float* __restrict__ bact,
    u32x4* __restrict__ Xf, int tbase)
{
  __shared__ float Wl[64][257];
  __shared__ float ol[32][64];
  __shared__ float xr[32][256];
  __shared__ float al[32];
  __shared__ float wal[100], bal[100], bol[256];
  int tl = blockIdx.x; int t = tbase + tl; int tid = threadIdx.x;
  for (int i = tid; i < 64*256; i += 256) Wl[i>>8][i&255] = Wobs[i];
  for (int i = tid; i < 32*64; i += 256)
    ol[i>>6][i&63] = obs[((size_t)(i>>6)*T_ + t)*OBS_ + (i&63)];
  if (tid < 32) al[tid] = act[(size_t)tid*T_ + t];
  if (tid < 100) { wal[tid] = Wact[tid]; bal[tid] = bact[tid]; }
  bol[tid] = bobs[tid];
  __syncthreads();
  {
    int k = tid;
    double accd[32];
#pragma unroll
    for (int r = 0; r < 32; ++r) accd[r] = 0.0;
    for (int kc = 0; kc < 64; kc += 8) {
      float w[8];
#pragma unroll
      for (int q = 0; q < 8; ++q) w[q] = Wl[kc+q][k];
#pragma unroll
      for (int r = 0; r < 32; ++r) {
#pragma unroll
        for (int q = 0; q < 8; ++q) accd[r] += (double)w[q]*(double)ol[r][kc+q];
      }
    }
#pragma unroll
    for (int r = 0; r < 32; ++r) xr[r][k] = fmaxf((float)(accd[r] + (double)bol[k]), 0.f);
  }
  __syncthreads();
  int g = tid >> 6, l = tid & 63;
  int r = l & 15, sub = l >> 4;
  for (int p = g; p < 24; p += 4) {
    int bg = p / 12, kk = p % 12;
    int b = bg*16 + r;
    unsigned short vh[8], vm[8], vl[8];
#pragma unroll
    for (int j = 0; j < 8; ++j) {
      int k = kk*32 + sub*8 + j;
      float x;
      if (k < 256)      x = xr[b][k];
      else if (k < 356) {
        double tmp = (double)al[b]*(double)wal[k-256] + (double)bal[k-256];
        x = fmaxf((float)tmp, 0.f);
      } else            x = 0.f;
      split3(x, vh[j], vm[j], vl[j]);
    }
    size_t base = ((((size_t)tl*2 + bg)*12 + kk)*3)*64 + l;
    Xf[base]       = pack8(vh);
    Xf[base + 64]  = pack8(vm);
    Xf[base + 128] = pack8(vl);
  }
}

// ---------------- P2: combined [W_lstm; U_lstm] B-frags, triple-split ----------------
__global__ __launch_bounds__(256) void k_prep_w(
    const float* __restrict__ Wl, const float* __restrict__ Ul,
    unsigned short* __restrict__ Wf)
{
  size_t gid = (size_t)blockIdx.x*256 + threadIdx.x;
  if (gid >= (size_t)896*2048) return;
  int k = (int)(gid >> 11), oc = (int)(gid & 2047);
  float v = 0.f;
  if (k < 356) v = Wl[(size_t)k*2048 + oc];
  else if (k >= 384) v = Ul[(size_t)(k-384)*2048 + oc];
  unsigned short vh, vm, vlo;
  split3(v, vh, vm, vlo);
  int g = oc >> 9, hs = (oc & 511) >> 4, u = oc & 15;
  int kk = k >> 5, sub = (k >> 3) & 3, j = k & 7;
  size_t e = ((((size_t)(hs*4 + g)*28 + kk)*3 + 0)*64 + (sub*16 + u))*8 + j;
  Wf[e]        = vh;
  Wf[e + 512]  = vm;
  Wf[e + 1024] = vlo;
}

// ---------------- P3: W_proj B-frags, triple-split, cols padded to 112 ----------------
__global__ __launch_bounds__(256) void k_prep_wp(
    const float* __restrict__ Wp, unsigned short* __restrict__ Wpf)
{
  int gid = blockIdx.x*256 + threadIdx.x;
  if (gid >= 512*112) return;
  int k = gid / 112, c = gid % 112;
  float v = (c < 100) ? Wp[(size_t)k*100 + c] : 0.f;
  unsigned short vh, vm, vlo;
  split3(v, vh, vm, vlo);
  int ct = c >> 4, cl = c & 15;
  int kk = k >> 5, sub = (k >> 3) & 3, j = k & 7;
  size_t e = (((size_t)(ct*16 + kk)*3 + 0)*64 + (sub*16 + cl))*8 + j;
  Wpf[e]        = vh;
  Wpf[e + 512]  = vm;
  Wpf[e + 1024] = vlo;
}

// ---------------- P4: zx = x-side gate preactivation (hoisted out of recurrence) ----------------
// grid = TC_*2*8 blocks; 256 thr = 4 waves (wave = gate); each block: 4 hs slices
__global__ __launch_bounds__(256) void k_prep_zx(
    const u32x4* __restrict__ Xf, const u32x4* __restrict__ Wf,
    float* __restrict__ zx)
{
  int bid = blockIdx.x;
  int hq = bid & 7, bg = (bid >> 3) & 1, tl = bid >> 4;
  int tid = threadIdx.x;
  int g = tid >> 6, lane = tid & 63;
  u32x4 xa[12][3];
  const u32x4* xp = Xf + (((size_t)tl*2 + bg)*12*3)*64 + lane;
#pragma unroll
  for (int f = 0; f < 12; ++f)
#pragma unroll
    for (int p = 0; p < 3; ++p) xa[f][p] = xp[(f*3+p)*64];
  for (int hi = 0; hi < 4; ++hi) {
    int hs = hq*4 + hi;
    const u32x4* bp = Wf + (((size_t)(hs*4 + g)*28)*3)*64 + lane;
    f32x4 a0={0,0,0,0},a1={0,0,0,0},a2={0,0,0,0},a3={0,0,0,0},a4={0,0,0,0},a5={0,0,0,0};
#pragma unroll
    for (int f = 0; f < 12; ++f) {
      u32x4 b0 = bp[(f*3+0)*64], b1 = bp[(f*3+1)*64], b2 = bp[(f*3+2)*64];
      a0 = __builtin_amdgcn_mfma_f32_16x16x32_bf16(as_b(xa[f][0]), as_b(b0), a0, 0,0,0);
      a1 = __builtin_amdgcn_mfma_f32_16x16x32_bf16(as_b(xa[f][0]), as_b(b1), a1, 0,0,0);
      a2 = __builtin_amdgcn_mfma_f32_16x16x32_bf16(as_b(xa[f][1]), as_b(b0), a2, 0,0,0);
      a3 = __builtin_amdgcn_mfma_f32_16x16x32_bf16(as_b(xa[f][0]), as_b(b2), a3, 0,0,0);
      a4 = __builtin_amdgcn_mfma_f32_16x16x32_bf16(as_b(xa[f][2]), as_b(b0), a4, 0,0,0);
      a5 = __builtin_amdgcn_mfma_f32_16x16x32_bf16(as_b(xa[f][1]), as_b(b1), a5, 0,0,0);
    }
    int col = lane & 15;
#pragma unroll
    for (int q = 0; q < 4; ++q) {
      int row = (lane>>4)*4 + q;
      double z = (((double)a3[q]+(double)a4[q])+(double)a5[q])
               + ((double)a1[q]+(double)a2[q]) + (double)a0[q];
      zx[(((size_t)tl*2 + bg)*16 + row)*2048 + g*512 + hs*16 + col] = (float)z;
    }
  }
}

// ---------------- R: persistent cooperative LSTM, fence-free sc1 exchange ----------------
// grid 64 = 2 batch-groups x 32 hidden-slices; 256 thr = 4 waves (wave = gate)
__global__ __launch_bounds__(256, 1) void k_rnn(
    const u32x4* __restrict__ Wf, const float* __restrict__ zx,
    const float* __restrict__ blstm,
    unsigned int* __restrict__ HC01, unsigned short* __restrict__ HC2,
    unsigned int* __restrict__ hg32, int* __restrict__ ctr,
    double* __restrict__ cstate, int tbase)
{
  __shared__ double zbuf[4][16][16];
  __shared__ unsigned int hb01[16][16];
  int wg = blockIdx.x, bg = wg >> 5, hs = wg & 31;
  int tid = threadIdx.x, w = tid >> 6, lane = tid & 63;
  // U-side weights resident: 16 frags x 3 planes = 192 VGPRs
  u32x4 Breg[16][3];
  {
    const u32x4* bp = Wf + (((size_t)(hs*4 + w)*28 + 12)*3)*64 + lane;
#pragma unroll
    for (int f = 0; f < 16; ++f)
#pragma unroll
      for (int p = 0; p < 3; ++p) Breg[f][p] = bp[(f*3+p)*64];
  }
  int gr = tid >> 4, gu = tid & 15;
  double bi  = (double)blstm[0*512 + hs*16 + gu];
  double bff = (double)blstm[1*512 + hs*16 + gu];
  double bgg = (double)blstm[2*512 + hs*16 + gu];
  double bo  = (double)blstm[3*512 + hs*16 + gu];
  double c = cstate[(size_t)(bg*16 + gr)*512 + hs*16 + gu];
  // pack-stage mapping (tid < 128)
  int r2 = tid >> 3, p8 = tid & 7;
  int hg0 = hs*16 + 2*p8;
  int pkk = hg0 >> 5, psub = (hg0 >> 3) & 3, pj = hg0 & 7;
  int plw = psub*16 + r2;

#pragma unroll 1
  for (int tl = 0; tl < TC_; ++tl) {
    int gt = tbase + tl;
    int sr = (gt + 2) % 3;
    // coherent h-frag loads (written by all WGs last step; no fence needed)
    u32x4 hf[16][2];
    {
      const unsigned int* hbase = hg32 + ((size_t)sr*2 + bg)*16*2*256 + lane*4;
#pragma unroll
      for (int kk = 0; kk < 16; ++kk) {
        hf[kk][0] = load_cohx4(hbase + ((size_t)kk*2 + 0)*256);
        hf[kk][1] = load_cohx4(hbase + ((size_t)kk*2 + 1)*256);
      }
    }
    // zx prefetch (used at gate stage)
    size_t zrow = (((size_t)tl*2 + bg)*16 + gr)*2048 + hs*16 + gu;
    float z0 = zx[zrow];
    float z1 = zx[zrow + 512];
    float z2 = zx[zrow + 1024];
    float z3 = zx[zrow + 1536];
    asm volatile("s_waitcnt vmcnt(0)" ::: "memory");
    __builtin_amdgcn_sched_barrier(0);
    f32x4 a0={0,0,0,0},a1={0,0,0,0},a2={0,0,0,0},a3={0,0,0,0},a4={0,0,0,0};
#pragma unroll
    for (int kk = 0; kk < 16; ++kk) {
      a0 = __builtin_amdgcn_mfma_f32_16x16x32_bf16(as_b(hf[kk][0]), as_b(Breg[kk][0]), a0, 0,0,0);
      a1 = __builtin_amdgcn_mfma_f32_16x16x32_bf16(as_b(hf[kk][0]), as_b(Breg[kk][1]), a1, 0,0,0);
      a2 = __builtin_amdgcn_mfma_f32_16x16x32_bf16(as_b(hf[kk][1]), as_b(Breg[kk][0]), a2, 0,0,0);
      a3 = __builtin_amdgcn_mfma_f32_16x16x32_bf16(as_b(hf[kk][0]), as_b(Breg[kk][2]), a3, 0,0,0);
      a4 = __builtin_amdgcn_mfma_f32_16x16x32_bf16(as_b(hf[kk][1]), as_b(Breg[kk][1]), a4, 0,0,0);
    }
#pragma unroll
    for (int q = 0; q < 4; ++q)
      zbuf[w][(lane>>4)*4 + q][lane & 15] =
        (((double)a3[q] + (double)a4[q]) + ((double)a1[q] + (double)a2[q])) + (double)a0[q];
    __syncthreads();
    { // gates in f64 (one thread per (batch-local row, hid-local col))
      double zi = zbuf[0][gr][gu] + (double)z0 + bi;
      double zf = zbuf[1][gr][gu] + (double)z1 + bff;
      double zg = zbuf[2][gr][gu] + (double)z2 + bgg;
      double zo = zbuf[3][gr][gu] + (double)z3 + bo;
      double i_ = 1.0/(1.0 + exp(-zi));
      double f_ = 1.0/(1.0 + exp(-zf));
      double g_ = tanh(zg);
      double o_ = 1.0/(1.0 + exp(-zo));
      c = f_*c + i_*g_;
      double h = o_*tanh(c);
      unsigned short h0, h1, h2;
      split3((float)h, h0, h1, h2);
      unsigned int w01 = (unsigned)h0 | ((unsigned)h1 << 16);
      size_t hcidx = (((size_t)tl*2 + bg)*16 + gr)*512 + hs*16 + gu;
      HC01[hcidx] = w01;      // normal stores: consumed by k_logits next dispatch
      HC2[hcidx]  = h2;
      hb01[gr][gu] = w01;
    }
    __syncthreads();
    if (tid < 128) { // pack pairs -> exchange ring, agent-coherent stores
      unsigned int a = hb01[r2][2*p8], b = hb01[r2][2*p8+1];
      unsigned int v0 = (a & 0xffffu) | (b << 16);          // plane0 pair
      unsigned int v1 = (a >> 16)     | (b & 0xffff0000u);  // plane1 pair
      size_t dg = ((((size_t)(gt%3)*2 + bg)*16 + pkk)*2 + 0)*256 + plw*4 + (pj>>1);
      __hip_atomic_store(&hg32[dg],       v0, __ATOMIC_RELAXED, __HIP_MEMORY_SCOPE_AGENT);
      __hip_atomic_store(&hg32[dg + 256], v1, __ATOMIC_RELAXED, __HIP_MEMORY_SCOPE_AGENT);
    }
    __syncthreads();   // drains all stores (vmcnt) before arrive
    if (tid == 0) {
      __hip_atomic_fetch_add(&ctr[bg*T_ + gt], 1, __ATOMIC_RELAXED, __HIP_MEMORY_SCOPE_AGENT);
      while (__hip_atomic_load(&ctr[bg*T_ + gt], __ATOMIC_RELAXED, __HIP_MEMORY_SCOPE_AGENT) < 32)
        __builtin_amdgcn_s_sleep(1);
    }
    __syncthreads();
  }
  cstate[(size_t)(bg*16 + gr)*512 + hs*16 + gu] = c;
}

// ---------------- L: logits + softmax(pi) for one chunk ----------------
__global__ __launch_bounds__(256) void k_logits(
    const unsigned int* __restrict__ HC01, const unsigned short* __restrict__ HC2,
    const u32x4* __restrict__ Wpf,
    const float* __restrict__ bproj, float* __restrict__ out, int tbase)
{
  __shared__ float zl[16][120];
  int bid = blockIdx.x;
  int tl = bid >> 1, bg = bid & 1;
  int tid = threadIdx.x;
  int w = tid >> 6, lane = tid & 63;
  int row = lane & 15, koff = (lane >> 4) * 8;
  u32x4 a[16][3];
  {
    const unsigned int* h01 = HC01 + (((size_t)tl*2 + bg)*16 + row)*512 + koff;
    const unsigned short* h2p = HC2 + (((size_t)tl*2 + bg)*16 + row)*512 + koff;
#pragma unroll
    for (int kk = 0; kk < 16; ++kk) {
      u32x4 c0 = *(const u32x4*)(h01 + 32*kk);
      u32x4 c1 = *(const u32x4*)(h01 + 32*kk + 4);
      u32x4 p0, p1;
      p0.x = (c0.x & 0xffffu) | (c0.y << 16);
      p0.y = (c0.z & 0xffffu) | (c0.w << 16);
      p0.z = (c1.x & 0xffffu) | (c1.y << 16);
      p0.w = (c1.z & 0xffffu) | (c1.w << 16);
      p1.x = (c0.x >> 16) | (c0.y & 0xffff0000u);
      p1.y = (c0.z >> 16) | (c0.w & 0xffff0000u);
      p1.z = (c1.x >> 16) | (c1.y & 0xffff0000u);
      p1.w = (c1.z >> 16) | (c1.w & 0xffff0000u);
      a[kk][0] = p0;
      a[kk][1] = p1;
      a[kk][2] = *(const u32x4*)(h2p + 32*kk);
    }
  }
  for (int ct = w; ct < 7; ct += 4) {
    f32x4 c0 = {0,0,0,0}, c1 = {0,0,0,0}, c2 = {0,0,0,0};
    f32x4 c3 = {0,0,0,0}, c4 = {0,0,0,0}, c5 = {0,0,0,0};
    const u32x4* bp2 = Wpf + ((size_t)ct*16*3)*64 + lane;
#pragma unroll
    for (int kk = 0; kk < 16; ++kk) {
      u32x4 b0 = bp2[(kk*3+0)*64], b1 = bp2[(kk*3+1)*64], b2 = bp2[(kk*3+2)*64];
      c0 = __builtin_amdgcn_mfma_f32_16x16x32_bf16(as_b(a[kk][0]), as_b(b0), c0, 0,0,0);
      c1 = __builtin_amdgcn_mfma_f32_16x16x32_bf16(as_b(a[kk][0]), as_b(b1), c1, 0,0,0);
      c2 = __builtin_amdgcn_mfma_f32_16x16x32_bf16(as_b(a[kk][1]), as_b(b0), c2, 0,0,0);
      c3 = __builtin_amdgcn_mfma_f32_16x16x32_bf16(as_b(a[kk][0]), as_b(b2), c3, 0,0,0);
      c4 = __builtin_amdgcn_mfma_f32_16x16x32_bf16(as_b(a[kk][2]), as_b(b0), c4, 0,0,0);
      c5 = __builtin_amdgcn_mfma_f32_16x16x32_bf16(as_b(a[kk][1]), as_b(b1), c5, 0,0,0);
    }
    int col = ct*16 + (lane & 15);
    float bv = (col < 100) ? bproj[col] : 0.f;
#pragma unroll
    for (int q = 0; q < 4; ++q) {
      double z = (((double)c3[q] + (double)c4[q]) + (double)c5[q])
               + ((double)c1[q] + (double)c2[q]) + (double)c0[q] + (double)bv;
      if (col < 120) zl[(lane>>4)*4 + q][col] = (float)z;
    }
  }
  __syncthreads();
  int srow = tid >> 4, l16 = tid & 15;
  float vv[7];
  float m = -1e30f;
#pragma unroll
  for (int k2 = 0; k2 < 7; ++k2) {
    int col = l16 + 16*k2;
    vv[k2] = (col < 100) ? zl[srow][col] : -1e30f;
    m = fmaxf(m, vv[k2]);
  }
#pragma unroll
  for (int d = 1; d < 16; d <<= 1) m = fmaxf(m, __shfl_xor(m, d, 64));
  float s = 0.f; float ek[7];
#pragma unroll
  for (int k2 = 0; k2 < 7; ++k2) {
    int col = l16 + 16*k2;
    ek[k2] = (col < 100) ? expf(vv[k2] - m) : 0.f;
    s += ek[k2];
  }
#pragma unroll
  for (int d = 1; d < 16; d <<= 1) s += __shfl_xor(s, d, 64);
  int t = tbase + tl; int b = bg*16 + srow;
  float* piout = out;
  float* lgout = out + 6553600ull;
#pragma unroll
  for (int k2 = 0; k2 < 7; ++k2) {
    int col = l16 + 16*k2;
    if (col < 100) {
      size_t idx = ((size_t)b*T_ + t)*100 + col;
      lgout[idx] = vv[k2];
      piout[idx] = ek[k2] / s;
    }
  }
}

// ---------------- A: argmax over batch axis (first-max semantics) ----------------
__global__ __launch_bounds__(128) void k_argmax(
    const float* __restrict__ lg, float* __restrict__ outA)
{
  int t = blockIdx.x, j = threadIdx.x;
  if (j >= 100) return;
  float best = lg[(size_t)t*100 + j];
  int bi = 0;
  for (int b = 1; b < 32; ++b) {
    float v = lg[((size_t)b*T_ + t)*100 + j];
    if (v > best) { best = v; bi = b; }
  }
  outA[(size_t)t*100 + j] = (float)bi;
}

extern "C" void kernel_launch(void* const* d_in, const int* in_sizes, int n_in,
                              void* d_out, int out_size, void* d_ws, size_t ws_size,
                              hipStream_t stream) {
  const float* obs  = (const float*)d_in[0];
  const float* act  = (const float*)d_in[1];
  const float* Wobs = (const float*)d_in[2];
  const float* bobs = (const float*)d_in[3];
  const float* Wact = (const float*)d_in[4];
  const float* bact = (const float*)d_in[5];
  const float* Wl   = (const float*)d_in[6];
  const float* Ul   = (const float*)d_in[7];
  const float* bl   = (const float*)d_in[8];
  const float* Wp   = (const float*)d_in[9];
  const float* bp   = (const float*)d_in[10];
  char* ws = (char*)d_ws;
  u32x4* Xf             = (u32x4*)(ws + XF_OFF);
  unsigned short* WfS   = (unsigned short*)(ws + WF_OFF);
  unsigned short* WpfS  = (unsigned short*)(ws + WPF_OFF);
  float* zx             = (float*)(ws + ZX_OFF);
  unsigned int* HC01    = (unsigned int*)(ws + HC01_OFF);
  unsigned short* HC2   = (unsigned short*)(ws + HC2_OFF);
  unsigned int* hg32    = (unsigned int*)(ws + HG_OFF);
  double* cstate        = (double*)(ws + CST_OFF);
  int* ctr              = (int*)(ws + CTR_OFF);
  float* out = (float*)d_out;

  // zero exchange ring + c-state + counters each launch (replay determinism)
  hipMemsetAsync(ws + HG_OFF, 0, HG_SZ + CST_SZ + CTR_SZ, stream);
  k_prep_w<<<7168, 256, 0, stream>>>(Wl, Ul, WfS);
  k_prep_wp<<<(512*112 + 255)/256, 256, 0, stream>>>(Wp, WpfS);
  for (int ch = 0; ch < NCH_; ++ch) {
    int tb = ch * TC_;
    k_prep_x<<<TC_, 256, 0, stream>>>(obs, act, Wobs, bobs, Wact, bact, Xf, tb);
    k_prep_zx<<<TC_*2*8, 256, 0, stream>>>((const u32x4*)Xf, (const u32x4*)WfS, zx);
    k_rnn<<<64, 256, 0, stream>>>((const u32x4*)WfS, zx, bl, HC01, HC2,
                                  hg32, ctr, cstate, tb);
    k_logits<<<TC_*2, 256, 0, stream>>>(HC01, HC2, (const u32x4*)WpfS, bp, out, tb);
  }
  k_argmax<<<T_, 128, 0, stream>>>(out + 6553600ull, out + 13107200ull);
}